// Round 4
// baseline (3400.352 us; speedup 1.0000x reference)
//
#include <hip/hip_runtime.h>

typedef _Float16 f16x8 __attribute__((ext_vector_type(8)));
typedef float    f32x4 __attribute__((ext_vector_type(4)));

constexpr int BATCH = 2048;
constexpr int SEQ   = 512;
constexpr int H     = 50;
constexpr int G4    = 200;  // 4*H gate rows
constexpr int NB    = 8;    // batch per block (N of the GEMM, padded to 16)
constexpr int NT    = 256;  // 4 waves
constexpr int MT    = 13;   // M tiles of 16 (208 >= 200)
constexpr int KS0   = 4;    // layer0 k-steps: K = 128 >= 102
constexpr int KS1   = 7;    // layer1 k-steps: K = 224 >= 200

__device__ __forceinline__ float sigm(float x) {
    return 1.0f / (1.0f + __expf(-x));
}
__device__ __forceinline__ float tanh_fast(float x) {
    float a = __expf(-2.0f * fabsf(x));
    float t = (1.0f - a) / (1.0f + a);
    return copysignf(t, x);
}
__device__ __forceinline__ _Float16 f16hi(float w) { return (_Float16)w; }
__device__ __forceinline__ _Float16 f16lo(float w) {
    _Float16 h = (_Float16)w; return (_Float16)(w - (float)h);
}
// B-panel frag-linear address (halfs): value (k, n)
__device__ __forceinline__ int baddr(int k, int n) {
    return (((k >> 5) * 64) + (((k >> 3) & 3) * 16) + n) * 8 + (k & 7);
}
// G (C-frag-linear) address (dwords): value (row, n)
__device__ __forceinline__ int gaddr(int row, int n) {
    return ((row >> 2) * 16 + n) * 4 + (row & 3);
}

__global__ __launch_bounds__(NT, 1) void lstm2_mfma(
    const float* __restrict__ x,
    const float* __restrict__ Wih0, const float* __restrict__ Whh0,
    const float* __restrict__ bih0, const float* __restrict__ bhh0,
    const float* __restrict__ Wih1, const float* __restrict__ Whh1,
    const float* __restrict__ bih1, const float* __restrict__ bhh1,
    const float* __restrict__ fcW,  const float* __restrict__ fcb,
    float* __restrict__ out)
{
    __shared__ _Float16 sB0[KS0 * 64 * 8];        // L0 B panel, 4 KB
    __shared__ _Float16 sB1[KS1 * 64 * 8];        // L1 B panel, 7 KB
    __shared__ float    sG[(MT * 4) * 16 * 4];    // gate preacts, 13.3 KB
    __shared__ float    sH2f[H * NB];             // final h2 (f32)

    const int t    = threadIdx.x;
    const int wave = t >> 6, lane = t & 63;
    const int quad = lane >> 4, nn = lane & 15;
    const int bbase = blockIdx.x * NB;

    // ---- zero B panels (k/n pads must be 0; combine only writes valid slots)
    for (int i = t; i < KS0 * 64 * 8; i += NT) sB0[i] = (_Float16)0.f;
    for (int i = t; i < KS1 * 64 * 8; i += NT) sB1[i] = (_Float16)0.f;

    // ---- build constant A-fragments in registers (wave w owns tiles w+4i) --
    f16x8 a0[4][KS0];
    f16x8 a1[4][KS1];
    f32x4 bias0v[4], bias1v[4];
    #pragma unroll
    for (int i = 0; i < 4; ++i) {
        const int  m   = wave + 4 * i;
        const bool mv  = (m < MT);
        const int  row = m * 16 + nn;          // A row for this lane
        const bool rv  = mv && (row < G4);
        #pragma unroll
        for (int q = 0; q < KS0; ++q) {
            #pragma unroll
            for (int j = 0; j < 8; ++j) {
                const int k = q * 32 + quad * 8 + j;
                _Float16 v = (_Float16)0.f;
                if (rv) {
                    if      (k < 50)  v = f16hi(Whh0[row * H + k]);
                    else if (k < 100) v = f16lo(Whh0[row * H + (k - 50)]);
                    else if (k == 100) v = f16hi(Wih0[row]);
                    else if (k == 101) v = f16lo(Wih0[row]);
                }
                a0[i][q][j] = v;
            }
        }
        #pragma unroll
        for (int q = 0; q < KS1; ++q) {
            #pragma unroll
            for (int j = 0; j < 8; ++j) {
                const int k = q * 32 + quad * 8 + j;
                _Float16 v = (_Float16)0.f;
                if (rv) {
                    if      (k < 50)  v = f16hi(Wih1[row * H + k]);
                    else if (k < 100) v = f16lo(Wih1[row * H + (k - 50)]);
                    else if (k < 150) v = f16hi(Whh1[row * H + (k - 100)]);
                    else if (k < 200) v = f16lo(Whh1[row * H + (k - 150)]);
                }
                a1[i][q][j] = v;
            }
        }
        #pragma unroll
        for (int r = 0; r < 4; ++r) {
            const int rw = m * 16 + quad * 4 + r;
            const bool bvv = mv && (rw < G4);
            bias0v[i][r] = bvv ? (bih0[rw] + bhh0[rw]) : 0.f;
            bias1v[i][r] = bvv ? (bih1[rw] + bhh1[rw]) : 0.f;
        }
    }

    float c0a = 0.f, c0b = 0.f, c1a = 0.f, c1b = 0.f;  // cell states (regs)

    __syncthreads();  // panels zeroed

    // prologue: x for step 0 into B0 rows 100/101 (h rows stay zero = h0init)
    if (t < NB) {
        float xv = x[(bbase + t) * SEQ + 0];
        sB0[baddr(100, t)] = f16hi(xv);
        sB0[baddr(101, t)] = f16lo(xv);
    }
    __syncthreads();

    #pragma unroll 1
    for (int s = 0; s < SEQ; ++s) {
        // ---- Phase A: L0 MFMA: G0 = A0 . B0 (bias in acc init) ----
        {
            f32x4 acc[4];
            #pragma unroll
            for (int i = 0; i < 4; ++i) acc[i] = bias0v[i];
            #pragma unroll
            for (int q = 0; q < KS0; ++q) {
                f16x8 b = *(const f16x8*)&sB0[(q * 64 + lane) * 8];
                #pragma unroll
                for (int i = 0; i < 4; ++i)
                    if (wave + 4 * i < MT)
                        acc[i] = __builtin_amdgcn_mfma_f32_16x16x32_f16(
                            a0[i][q], b, acc[i], 0, 0, 0);
            }
            #pragma unroll
            for (int i = 0; i < 4; ++i) {
                const int m = wave + 4 * i;
                if (m < MT)
                    *(f32x4*)&sG[((m * 4 + quad) * 16 + nn) * 4] = acc[i];
            }
        }
        __syncthreads();

        // ---- Phase B: L0 combine -> c0, h1 -> B0(next step) & B1(now) ----
        #pragma unroll
        for (int rep = 0; rep < 2; ++rep) {
            const int it = t + rep * NT;
            if (it < H * NB) {
                const int j = it >> 3, b = it & 7;
                float gi = sG[gaddr(j,        b)];
                float gf = sG[gaddr(j +  50,  b)];
                float gg = sG[gaddr(j + 100,  b)];
                float go = sG[gaddr(j + 150,  b)];
                float& c = rep ? c0b : c0a;
                c = sigm(gf) * c + sigm(gi) * tanh_fast(gg);
                float h = sigm(go) * tanh_fast(c);
                _Float16 hh = f16hi(h), hl = f16lo(h);
                sB0[baddr(j,      b)] = hh;  sB0[baddr(50 + j, b)] = hl;
                sB1[baddr(j,      b)] = hh;  sB1[baddr(50 + j, b)] = hl;
            }
        }
        if (t < NB) {  // x for step s+1
            const int sn = (s < SEQ - 1) ? s + 1 : s;
            float xv = x[(bbase + t) * SEQ + sn];
            sB0[baddr(100, t)] = f16hi(xv);
            sB0[baddr(101, t)] = f16lo(xv);
        }
        __syncthreads();

        // ---- Phase C: L1 MFMA: G1 = A1 . B1 ----
        {
            f32x4 acc[4];
            #pragma unroll
            for (int i = 0; i < 4; ++i) acc[i] = bias1v[i];
            #pragma unroll
            for (int q = 0; q < KS1; ++q) {
                f16x8 b = *(const f16x8*)&sB1[(q * 64 + lane) * 8];
                #pragma unroll
                for (int i = 0; i < 4; ++i)
                    if (wave + 4 * i < MT)
                        acc[i] = __builtin_amdgcn_mfma_f32_16x16x32_f16(
                            a1[i][q], b, acc[i], 0, 0, 0);
            }
            #pragma unroll
            for (int i = 0; i < 4; ++i) {
                const int m = wave + 4 * i;
                if (m < MT)
                    *(f32x4*)&sG[((m * 4 + quad) * 16 + nn) * 4] = acc[i];
            }
        }
        __syncthreads();

        // ---- Phase D: L1 combine -> c1, h2 -> B1 rows 100..199 (next step) --
        #pragma unroll
        for (int rep = 0; rep < 2; ++rep) {
            const int it = t + rep * NT;
            if (it < H * NB) {
                const int j = it >> 3, b = it & 7;
                float gi = sG[gaddr(j,        b)];
                float gf = sG[gaddr(j +  50,  b)];
                float gg = sG[gaddr(j + 100,  b)];
                float go = sG[gaddr(j + 150,  b)];
                float& c = rep ? c1b : c1a;
                c = sigm(gf) * c + sigm(gi) * tanh_fast(gg);
                float h = sigm(go) * tanh_fast(c);
                _Float16 hh = f16hi(h), hl = f16lo(h);
                sB1[baddr(100 + j, b)] = hh;
                sB1[baddr(150 + j, b)] = hl;
                if (s == SEQ - 1) sH2f[j * NB + b] = h;
            }
        }
        __syncthreads();
    }

    // ---- FC epilogue: out[b] = fcW . h2_last[b] + fcb ----
    if (t < NB) {
        float sum = fcb[0];
        #pragma unroll
        for (int j = 0; j < H; ++j) sum += fcW[j] * sH2f[j * NB + t];
        out[bbase + t] = sum;
    }
}

extern "C" void kernel_launch(void* const* d_in, const int* in_sizes, int n_in,
                              void* d_out, int out_size, void* d_ws, size_t ws_size,
                              hipStream_t stream)
{
    const float* x    = (const float*)d_in[0];
    const float* Wih0 = (const float*)d_in[1];
    const float* Whh0 = (const float*)d_in[2];
    const float* bih0 = (const float*)d_in[3];
    const float* bhh0 = (const float*)d_in[4];
    const float* Wih1 = (const float*)d_in[5];
    const float* Whh1 = (const float*)d_in[6];
    const float* bih1 = (const float*)d_in[7];
    const float* bhh1 = (const float*)d_in[8];
    const float* fcW  = (const float*)d_in[9];
    const float* fcb  = (const float*)d_in[10];

    lstm2_mfma<<<BATCH / NB, NT, 0, stream>>>(
        x, Wih0, Whh0, bih0, bhh0, Wih1, Whh1, bih1, bhh1, fcW, fcb,
        (float*)d_out);
}

// Round 5
// 662.089 us; speedup vs baseline: 5.1358x; 5.1358x over previous
//
#include <hip/hip_runtime.h>

typedef _Float16 f16x8 __attribute__((ext_vector_type(8)));
typedef float    f32x4 __attribute__((ext_vector_type(4)));

constexpr int BATCH = 2048;
constexpr int SEQ   = 512;
constexpr int H     = 50;
constexpr int G4    = 200;  // 4*H gate rows
constexpr int NB    = 8;    // batch per block -> 256 blocks = 1 per CU
constexpr int NT    = 512;  // 8 waves, 2 per SIMD
constexpr int MT    = 13;   // M tiles of 16 (208 >= 200); wave w owns m=w, w+8
constexpr int KQ    = 8;    // B-panel k-chunks of 32 (K=256)

// ---- fast native transcendentals (v_exp_f32 / v_rcp_f32) ----
__device__ __forceinline__ float fexp2(float x) {
#if __has_builtin(__builtin_amdgcn_exp2f)
    return __builtin_amdgcn_exp2f(x);
#else
    return exp2f(x);
#endif
}
__device__ __forceinline__ float frcp(float x) {
#if __has_builtin(__builtin_amdgcn_rcpf)
    return __builtin_amdgcn_rcpf(x);
#else
    return 1.0f / x;
#endif
}
__device__ __forceinline__ float sigm(float x) {
    return frcp(1.0f + fexp2(-1.4426950408889634f * x));
}
__device__ __forceinline__ float tanh_fast(float x) {
    float a = fexp2(-2.8853900817779268f * fabsf(x));
    float t = (1.0f - a) * frcp(1.0f + a);
    return copysignf(t, x);
}
__device__ __forceinline__ _Float16 f16hi(float w) { return (_Float16)w; }
__device__ __forceinline__ _Float16 f16lo(float w) {
    _Float16 h = (_Float16)w; return (_Float16)(w - (float)h);
}
// B-panel frag-linear address (halfs) for value (k, n), k<256, n<16
__device__ __forceinline__ int baddr(int k, int n) {
    return (((k >> 5) * 64) + (((k >> 3) & 3) * 16) + n) * 8 + (k & 7);
}
// G buffer (C-frag-linear) address (dwords) for value (row, n)
__device__ __forceinline__ int gaddr(int row, int n) {
    return ((row >> 2) * 16 + n) * 4 + (row & 3);
}

// B-panel k-map:  0..49 h1_hi | 50..99 h1_lo | 100,101 x_hi,x_lo |
//                 128..177 h2_hi | 178..227 h2_lo | rest zero
// A0 (L0) covers k 0..101 (q=0..3); A1 (L1) covers k 0..99 & 128..227 (q=0..7)

__global__ __launch_bounds__(NT, 1) void lstm2_pipe(
    const float* __restrict__ x,
    const float* __restrict__ Wih0, const float* __restrict__ Whh0,
    const float* __restrict__ bih0, const float* __restrict__ bhh0,
    const float* __restrict__ Wih1, const float* __restrict__ Whh1,
    const float* __restrict__ bih1, const float* __restrict__ bhh1,
    const float* __restrict__ fcW,  const float* __restrict__ fcb,
    float* __restrict__ out)
{
    __shared__ _Float16 sB[KQ * 64 * 8];          // shared B panel, 8 KB
    __shared__ float    sG0[MT * 4 * 16 * 4];     // L0 gate preacts, 13.3 KB
    __shared__ float    sG1[MT * 4 * 16 * 4];     // L1 gate preacts, 13.3 KB
    __shared__ float    sH2f[H * NB];             // final h2 (f32)

    const int t    = threadIdx.x;
    const int wave = t >> 6, lane = t & 63;
    const int quad = lane >> 4, nn = lane & 15;
    const int bbase = blockIdx.x * NB;

    // zero B panel (pads must stay 0 forever)
    for (int i = t; i < KQ * 64 * 8; i += NT) sB[i] = (_Float16)0.f;

    // ---- build constant A-fragments in registers; wave w owns m = w, w+8 ----
    const bool m1v = (wave + 8 < MT);
    f16x8 a0[2][4];
    f16x8 a1[2][KQ];
    f32x4 bias0v[2], bias1v[2];
    #pragma unroll
    for (int i = 0; i < 2; ++i) {
        const int  m   = wave + 8 * i;
        const bool mv  = (i == 0) || m1v;
        const int  row = m * 16 + nn;
        const bool rv  = mv && (row < G4);
        #pragma unroll
        for (int q = 0; q < 4; ++q) {
            #pragma unroll
            for (int j = 0; j < 8; ++j) {
                const int k = q * 32 + quad * 8 + j;
                _Float16 v = (_Float16)0.f;
                if (rv) {
                    if      (k < 50)   v = f16hi(Whh0[row * H + k]);
                    else if (k < 100)  v = f16lo(Whh0[row * H + (k - 50)]);
                    else if (k == 100) v = f16hi(Wih0[row]);
                    else if (k == 101) v = f16lo(Wih0[row]);
                }
                a0[i][q][j] = v;
            }
        }
        #pragma unroll
        for (int q = 0; q < KQ; ++q) {
            #pragma unroll
            for (int j = 0; j < 8; ++j) {
                const int k = q * 32 + quad * 8 + j;
                _Float16 v = (_Float16)0.f;
                if (rv) {
                    if      (k < 50)             v = f16hi(Wih1[row * H + k]);
                    else if (k < 100)            v = f16lo(Wih1[row * H + (k - 50)]);
                    else if (k >= 128 && k < 178) v = f16hi(Whh1[row * H + (k - 128)]);
                    else if (k >= 178 && k < 228) v = f16lo(Whh1[row * H + (k - 178)]);
                }
                a1[i][q][j] = v;
            }
        }
        #pragma unroll
        for (int r = 0; r < 4; ++r) {
            const int rw = m * 16 + quad * 4 + r;
            const bool bv = mv && (rw < G4);
            bias0v[i][r] = bv ? (bih0[rw] + bhh0[rw]) : 0.f;
            bias1v[i][r] = bv ? (bih1[rw] + bhh1[rw]) : 0.f;
        }
    }

    // combine mapping: thread t<400 owns (hidden j, batch b)
    const int j = t >> 3, b = t & 7;
    const bool act = (t < H * NB);
    float c0 = 0.f, c1 = 0.f;

    __syncthreads();
    // prologue: x(0) into rows 100/101
    if (t < NB) {
        float xv = x[(bbase + t) * SEQ + 0];
        sB[baddr(100, t)] = f16hi(xv);
        sB[baddr(101, t)] = f16lo(xv);
    }
    __syncthreads();

    #pragma unroll 1
    for (int s = 0; s <= SEQ; ++s) {
        // ================= Phase 1: both GEMMs =================
        f16x8 bq[KQ];
        #pragma unroll
        for (int q = 0; q < KQ; ++q)
            bq[q] = *(const f16x8*)&sB[(q * 64 + lane) * 8];

        if (s < SEQ) {   // L0 gemm for step s: uses h1(s-1), x(s)
            f32x4 acc0 = bias0v[0], acc1 = bias0v[1];
            #pragma unroll
            for (int q = 0; q < 4; ++q) {
                acc0 = __builtin_amdgcn_mfma_f32_16x16x32_f16(a0[0][q], bq[q], acc0, 0, 0, 0);
                if (m1v)
                    acc1 = __builtin_amdgcn_mfma_f32_16x16x32_f16(a0[1][q], bq[q], acc1, 0, 0, 0);
            }
            *(f32x4*)&sG0[((wave * 4 + quad) * 16 + nn) * 4] = acc0;
            if (m1v)
                *(f32x4*)&sG0[(((wave + 8) * 4 + quad) * 16 + nn) * 4] = acc1;
        }
        if (s >= 1) {    // L1 gemm for step s-1: uses h1(s-1), h2(s-2)
            f32x4 acc0 = bias1v[0], acc1 = bias1v[1];
            #pragma unroll
            for (int q = 0; q < KQ; ++q) {
                acc0 = __builtin_amdgcn_mfma_f32_16x16x32_f16(a1[0][q], bq[q], acc0, 0, 0, 0);
                if (m1v)
                    acc1 = __builtin_amdgcn_mfma_f32_16x16x32_f16(a1[1][q], bq[q], acc1, 0, 0, 0);
            }
            *(f32x4*)&sG1[((wave * 4 + quad) * 16 + nn) * 4] = acc0;
            if (m1v)
                *(f32x4*)&sG1[(((wave + 8) * 4 + quad) * 16 + nn) * 4] = acc1;
        }
        __syncthreads();

        // ================= Phase 2: both combines =================
        float xv = 0.f;
        const bool xl = (t < NB) && (s + 1 < SEQ);
        if (xl) xv = x[(bbase + t) * SEQ + (s + 1)];   // prefetch early

        if (act && s < SEQ) {         // L0 combine for step s -> h1(s)
            float gi = sG0[gaddr(j,        b)];
            float gf = sG0[gaddr(j +  50,  b)];
            float gg = sG0[gaddr(j + 100,  b)];
            float go = sG0[gaddr(j + 150,  b)];
            c0 = sigm(gf) * c0 + sigm(gi) * tanh_fast(gg);
            float h = sigm(go) * tanh_fast(c0);
            sB[baddr(j,      b)] = f16hi(h);
            sB[baddr(j + 50, b)] = f16lo(h);
        }
        if (act && s >= 1) {          // L1 combine for step s-1 -> h2(s-1)
            float gi = sG1[gaddr(j,        b)];
            float gf = sG1[gaddr(j +  50,  b)];
            float gg = sG1[gaddr(j + 100,  b)];
            float go = sG1[gaddr(j + 150,  b)];
            c1 = sigm(gf) * c1 + sigm(gi) * tanh_fast(gg);
            float h = sigm(go) * tanh_fast(c1);
            if (s == SEQ) {
                sH2f[j * NB + b] = h;            // h2(511) for the FC
            } else {
                sB[baddr(j + 128, b)] = f16hi(h);
                sB[baddr(j + 178, b)] = f16lo(h);
            }
        }
        if (xl) {                     // x(s+1) into rows 100/101
            sB[baddr(100, t)] = f16hi(xv);
            sB[baddr(101, t)] = f16lo(xv);
        }
        __syncthreads();
    }

    // ---- FC epilogue: out[b] = fcW . h2_last[b] + fcb ----
    if (t < NB) {
        float sum = fcb[0];
        #pragma unroll
        for (int jj = 0; jj < H; ++jj) sum += fcW[jj] * sH2f[jj * NB + t];
        out[bbase + t] = sum;
    }
}

extern "C" void kernel_launch(void* const* d_in, const int* in_sizes, int n_in,
                              void* d_out, int out_size, void* d_ws, size_t ws_size,
                              hipStream_t stream)
{
    const float* x    = (const float*)d_in[0];
    const float* Wih0 = (const float*)d_in[1];
    const float* Whh0 = (const float*)d_in[2];
    const float* bih0 = (const float*)d_in[3];
    const float* bhh0 = (const float*)d_in[4];
    const float* Wih1 = (const float*)d_in[5];
    const float* Whh1 = (const float*)d_in[6];
    const float* bih1 = (const float*)d_in[7];
    const float* bhh1 = (const float*)d_in[8];
    const float* fcW  = (const float*)d_in[9];
    const float* fcb  = (const float*)d_in[10];

    lstm2_pipe<<<BATCH / NB, NT, 0, stream>>>(
        x, Wih0, Whh0, bih0, bhh0, Wih1, Whh1, bih1, bhh1, fcW, fcb,
        (float*)d_out);
}

// Round 6
// 639.649 us; speedup vs baseline: 5.3160x; 1.0351x over previous
//
#include <hip/hip_runtime.h>

typedef _Float16 f16x8 __attribute__((ext_vector_type(8)));
typedef float    f32x4 __attribute__((ext_vector_type(4)));

constexpr int BATCH = 2048;
constexpr int SEQ   = 512;
constexpr int H     = 50;
constexpr int NB    = 8;    // batch per block -> 256 blocks = 1 per CU
constexpr int NT    = 512;  // 8 waves, 2 per SIMD
constexpr int MT    = 13;   // M tiles of 16 (208 rows >= 200)
constexpr int KQ    = 7;    // panel k-chunks of 32 (K=224)

__device__ __forceinline__ float fexp2(float x) { return __builtin_amdgcn_exp2f(x); }
__device__ __forceinline__ float frcp(float x)  { return __builtin_amdgcn_rcpf(x); }
__device__ __forceinline__ float sigm(float x) {
    return frcp(1.0f + fexp2(-1.4426950408889634f * x));
}
__device__ __forceinline__ float tanh_fast(float x) {
    float a = fexp2(-2.8853900817779268f * fabsf(x));
    return copysignf((1.0f - a) * frcp(1.0f + a), x);
}
__device__ __forceinline__ _Float16 f16hi(float w) { return (_Float16)w; }
__device__ __forceinline__ _Float16 f16lo(float w) {
    _Float16 h = (_Float16)w; return (_Float16)(w - (float)h);
}
// B-panel frag-linear address (halfs) for value (k, n), k<224, n<16
__device__ __forceinline__ int baddr(int k, int n) {
    return (((k >> 5) * 64) + (((k >> 3) & 3) * 16) + n) * 8 + (k & 7);
}
union H2U { unsigned u; _Float16 h[2]; };

// Panel k-map: 0..49 h1_hi | 50..99 h1_lo | 100,101 x_hi,x_lo |
//              112..161 h2_hi | 162..211 h2_lo | rest 0
// GATE PERMUTATION: A/C physical row (within tile m) w ↔ hidden j = m*4+(w>>2),
// gate = w&3  (logical W row = gate*50 + j).  C/D: lane(quad,nn) reg r ->
// row quad*4+r -> (j = m*4+quad, gate r), col nn = batch.  So one lane's f32x4
// acc = {i,f,g,o} of one (j,b): combine reads are a single b128 from sG.

__global__ __launch_bounds__(NT, 2) void lstm2_perm(
    const float* __restrict__ x,
    const float* __restrict__ Wih0, const float* __restrict__ Whh0,
    const float* __restrict__ bih0, const float* __restrict__ bhh0,
    const float* __restrict__ Wih1, const float* __restrict__ Whh1,
    const float* __restrict__ bih1, const float* __restrict__ bhh1,
    const float* __restrict__ fcW,  const float* __restrict__ fcb,
    float* __restrict__ out)
{
    __shared__ _Float16 sB[KQ * 64 * 8];        // shared B panel, 7 KB
    __shared__ float    sG0[MT * 256];          // L0 gates, C-frag, 13.3 KB
    __shared__ float    sG1[MT * 256];          // L1 gates, 13.3 KB
    __shared__ unsigned sXu[SEQ * NB];          // pre-split x (hi,lo), 16 KB
    __shared__ float    sH2f[H * NB];           // final h2

    const int t    = threadIdx.x;
    const int wave = t >> 6, lane = t & 63;
    const int quad = lane >> 4, nn = lane & 15;
    const int bbase = blockIdx.x * NB;

    // zero panel (pads must stay 0 forever)
    for (int i = t; i < KQ * 64 * 8; i += NT) sB[i] = (_Float16)0.f;

    // ---- pre-stage ALL x as f16 hi/lo pairs (coalesced global reads) ----
    for (int i = t; i < NB * SEQ; i += NT) {
        const int b = i >> 9, s = i & (SEQ - 1);
        float xv = x[(bbase + b) * SEQ + s];
        H2U p; p.h[0] = f16hi(xv); p.h[1] = f16lo(xv);
        sXu[s * NB + b] = p.u;
    }

    // ---- constant A-fragments (gate-permuted rows); wave w owns m=w, w+8 ----
    const bool m1v = (wave + 8 < MT);
    f16x8 a0[2][4];
    f16x8 a1[2][KQ];
    f32x4 b0v[2], b1v[2];
    #pragma unroll
    for (int i = 0; i < 2; ++i) {
        const int  m    = wave + 8 * i;
        const bool mv   = (i == 0) || m1v;
        const int  jr   = m * 4 + (nn >> 2);     // hidden unit of A phys row nn
        const int  gate = nn & 3;
        const bool rv   = mv && (jr < H);
        const int  lrow = gate * H + jr;         // logical W row
        #pragma unroll
        for (int q = 0; q < 4; ++q) {
            #pragma unroll
            for (int j = 0; j < 8; ++j) {
                const int k = q * 32 + quad * 8 + j;
                _Float16 v = (_Float16)0.f;
                if (rv) {
                    if      (k < 50)   v = f16hi(Whh0[lrow * H + k]);
                    else if (k < 100)  v = f16lo(Whh0[lrow * H + (k - 50)]);
                    else if (k == 100) v = f16hi(Wih0[lrow]);
                    else if (k == 101) v = f16lo(Wih0[lrow]);
                }
                a0[i][q][j] = v;
            }
        }
        #pragma unroll
        for (int q = 0; q < KQ; ++q) {
            #pragma unroll
            for (int j = 0; j < 8; ++j) {
                const int k = q * 32 + quad * 8 + j;
                _Float16 v = (_Float16)0.f;
                if (rv) {
                    if      (k < 50)              v = f16hi(Wih1[lrow * H + k]);
                    else if (k < 100)             v = f16lo(Wih1[lrow * H + (k - 50)]);
                    else if (k >= 112 && k < 162) v = f16hi(Whh1[lrow * H + (k - 112)]);
                    else if (k >= 162 && k < 212) v = f16lo(Whh1[lrow * H + (k - 162)]);
                }
                a1[i][q][j] = v;
            }
        }
        const int jq = m * 4 + quad;             // hidden unit of acc regs
        #pragma unroll
        for (int r = 0; r < 4; ++r) {
            const bool bv = mv && (jq < H);
            b0v[i][r] = bv ? (bih0[r * H + jq] + bhh0[r * H + jq]) : 0.f;
            b1v[i][r] = bv ? (bih1[r * H + jq] + bhh1[r * H + jq]) : 0.f;
        }
    }

    // combine mapping: thread t<400 owns (hidden j, batch b)
    const int cj = t >> 3, cb = t & 7;
    const bool act = (t < H * NB);
    float c0 = 0.f, c1 = 0.f;

    __syncthreads();
    if (t < NB) {                                 // x(0) into panel
        H2U p; p.u = sXu[t];
        sB[baddr(100, t)] = p.h[0];
        sB[baddr(101, t)] = p.h[1];
    }
    __syncthreads();

    #pragma unroll 1
    for (int s = 0; s <= SEQ; ++s) {
        // ============ Phase 1: both GEMMs (read panel, write sG) ============
        f16x8 bq[KQ];
        #pragma unroll
        for (int q = 0; q < KQ; ++q)
            bq[q] = *(const f16x8*)&sB[(q * 64 + lane) * 8];

        if (s < SEQ) {    // L0 for step s: h1(s-1), x(s)
            f32x4 acc0 = b0v[0], acc1 = b0v[1];
            #pragma unroll
            for (int q = 0; q < 4; ++q) {
                acc0 = __builtin_amdgcn_mfma_f32_16x16x32_f16(a0[0][q], bq[q], acc0, 0, 0, 0);
                if (m1v)
                    acc1 = __builtin_amdgcn_mfma_f32_16x16x32_f16(a0[1][q], bq[q], acc1, 0, 0, 0);
            }
            *(f32x4*)&sG0[((wave * 4 + quad) * 16 + nn) * 4] = acc0;
            if (m1v)
                *(f32x4*)&sG0[(((wave + 8) * 4 + quad) * 16 + nn) * 4] = acc1;
        }
        if (s >= 1) {     // L1 for step s-1: h1(s-1), h2(s-2); even/odd chains
            f32x4 e0 = b1v[0], e1 = b1v[1];
            f32x4 o0 = {0.f, 0.f, 0.f, 0.f}, o1 = {0.f, 0.f, 0.f, 0.f};
            #pragma unroll
            for (int q = 0; q < KQ; q += 2) {
                e0 = __builtin_amdgcn_mfma_f32_16x16x32_f16(a1[0][q], bq[q], e0, 0, 0, 0);
                if (m1v)
                    e1 = __builtin_amdgcn_mfma_f32_16x16x32_f16(a1[1][q], bq[q], e1, 0, 0, 0);
            }
            #pragma unroll
            for (int q = 1; q < KQ; q += 2) {
                o0 = __builtin_amdgcn_mfma_f32_16x16x32_f16(a1[0][q], bq[q], o0, 0, 0, 0);
                if (m1v)
                    o1 = __builtin_amdgcn_mfma_f32_16x16x32_f16(a1[1][q], bq[q], o1, 0, 0, 0);
            }
            *(f32x4*)&sG1[((wave * 4 + quad) * 16 + nn) * 4] = e0 + o0;
            if (m1v)
                *(f32x4*)&sG1[(((wave + 8) * 4 + quad) * 16 + nn) * 4] = e1 + o1;
        }
        __syncthreads();

        // ============ Phase 2: combines (read sG, write panel) ============
        if (t < NB && s + 1 < SEQ) {              // x(s+1) from LDS stage
            H2U p; p.u = sXu[(s + 1) * NB + t];
            sB[baddr(100, t)] = p.h[0];
            sB[baddr(101, t)] = p.h[1];
        }
        if (act && s < SEQ) {                     // L0 combine -> h1(s)
            f32x4 g = *(const f32x4*)&sG0[(cj * 16 + cb) * 4];
            c0 = sigm(g[1]) * c0 + sigm(g[0]) * tanh_fast(g[2]);
            float h = sigm(g[3]) * tanh_fast(c0);
            sB[baddr(cj,      cb)] = f16hi(h);
            sB[baddr(cj + 50, cb)] = f16lo(h);
        }
        if (act && s >= 1) {                      // L1 combine -> h2(s-1)
            f32x4 g = *(const f32x4*)&sG1[(cj * 16 + cb) * 4];
            c1 = sigm(g[1]) * c1 + sigm(g[0]) * tanh_fast(g[2]);
            float h = sigm(g[3]) * tanh_fast(c1);
            if (s == SEQ) {
                sH2f[t] = h;                      // h2(511): t = cj*8+cb
            } else {
                sB[baddr(cj + 112, cb)] = f16hi(h);
                sB[baddr(cj + 162, cb)] = f16lo(h);
            }
        }
        __syncthreads();
    }

    // ---- FC epilogue: out[b] = fcW . h2_last[b] + fcb ----
    if (t < NB) {
        float sum = fcb[0];
        #pragma unroll
        for (int jj = 0; jj < H; ++jj) sum += fcW[jj] * sH2f[jj * NB + t];
        out[bbase + t] = sum;
    }
}

extern "C" void kernel_launch(void* const* d_in, const int* in_sizes, int n_in,
                              void* d_out, int out_size, void* d_ws, size_t ws_size,
                              hipStream_t stream)
{
    const float* x    = (const float*)d_in[0];
    const float* Wih0 = (const float*)d_in[1];
    const float* Whh0 = (const float*)d_in[2];
    const float* bih0 = (const float*)d_in[3];
    const float* bhh0 = (const float*)d_in[4];
    const float* Wih1 = (const float*)d_in[5];
    const float* Whh1 = (const float*)d_in[6];
    const float* bih1 = (const float*)d_in[7];
    const float* bhh1 = (const float*)d_in[8];
    const float* fcW  = (const float*)d_in[9];
    const float* fcb  = (const float*)d_in[10];

    lstm2_perm<<<BATCH / NB, NT, 0, stream>>>(
        x, Wih0, Whh0, bih0, bhh0, Wih1, Whh1, bih1, bhh1, fcW, fcb,
        (float*)d_out);
}